// Round 13
// baseline (6830.445 us; speedup 1.0000x reference)
//
#include <hip/hip_runtime.h>
#include <hip/hip_bf16.h>

#define T_STEPS 512
#define BATCH   128
#define IN      512
#define HID     512
#define KTOT    1024   // IN + HID fused
#define BT      16     // batch rows per group
#define JT      32     // hidden cols per block
#define NJT     16     // blocks per group (j tiles)
#define BH      (BATCH * HID)

typedef __attribute__((ext_vector_type(8))) short bf16x8;
typedef __attribute__((ext_vector_type(4))) float f32x4;
typedef __attribute__((ext_vector_type(4))) unsigned int u32x4;

static __device__ __forceinline__ unsigned short f2bf(float f) {
    unsigned u = __float_as_uint(f);
    unsigned r = (u + 0x7FFFu + ((u >> 16) & 1u)) >> 16;   // RNE, finite inputs only
    return (unsigned short)r;
}
static __device__ __forceinline__ ushort4 pack4(float4 v) {
    ushort4 b4;
    b4.x = f2bf(v.x); b4.y = f2bf(v.y); b4.z = f2bf(v.z); b4.w = f2bf(v.w);
    return b4;
}
static __device__ __forceinline__ float tanh_fast(float x) {
    return 1.f - 2.f * __builtin_amdgcn_rcpf(1.f + __expf(2.f * x));
}
static __device__ __forceinline__ bool vld4(u32x4 v, unsigned tgtw) {
    return ((v[0] & 0xFFFF0000u) == tgtw) & ((v[1] & 0xFFFF0000u) == tgtw) &
           ((v[2] & 0xFFFF0000u) == tgtw) & ((v[3] & 0xFFFF0000u) == tgtw);
}
template<int I>
static __device__ __forceinline__ float qbcast(float x) {   // broadcast lane (quad base + I) within each quad
    return __uint_as_float((unsigned)__builtin_amdgcn_update_dpp(
        (int)__float_as_uint(x), (int)__float_as_uint(x), I * 0x55, 0xF, 0xF, false));
}

// ---- prep: fuse W_ih|W_hh into bf16 [2048][1024], bias = b_ih + b_hh ----
__global__ void prep_kernel(const float* __restrict__ W_ih, const float* __restrict__ W_hh,
                            const float* __restrict__ b_ih, const float* __restrict__ b_hh,
                            unsigned short* __restrict__ Wc, float* __restrict__ bias) {
    int idx = blockIdx.x * blockDim.x + threadIdx.x;   // 0 .. 2048*256-1 float4 granules
    int row = idx >> 8;
    int kq  = idx & 255;
    const float* src = (kq < 128) ? (W_ih + (size_t)row * IN + kq * 4)
                                  : (W_hh + (size_t)row * HID + (kq - 128) * 4);
    float4 v = *(const float4*)src;
    *(ushort4*)(Wc + (size_t)row * KTOT + kq * 4) = pack4(v);
    if (idx < 4 * HID) bias[idx] = b_ih[idx] + b_hh[idx];
}

// ---- persistent LSTM kernel: 512 thr, 8 waves, 2 batch groups x 16 rows x 32 cols ----
__global__ __launch_bounds__(512, 2) void lstm_kernel(
    const float* __restrict__ xin, const float* __restrict__ h0,
    const float* __restrict__ c0, const unsigned short* __restrict__ Wc,
    const float* __restrict__ bias, float* __restrict__ out,
    unsigned* __restrict__ hseq)   // [2][BATCH][HID] u32: (seq<<16)|bf16(h)
{
    const int tid  = threadIdx.x;
    const int bid  = blockIdx.x;
    const int gp   = bid & 3;        // group pair 0..3
    const int jt   = bid >> 2;       // j tile 0..15 (32 cols each)
    const int btA  = gp * 2;         // batch groups
    const int btB  = gp * 2 + 1;
    const int wv   = tid >> 6;       // wave 0..7
    const int lane = tid & 63;
    const int ln15 = lane & 15;
    const int khi  = lane >> 4;

    // LDS 96KB: xA [0,16K) xB [16K,32K) hA [32K,64K) hB [64K,96K)
    __shared__ __align__(16) unsigned char smem[98304];

    const int gown = ln15 & 3;              // lane's gate (0=i,1=f,2=g,3=o)
    const int jj   = ln15 >> 2;             // j sub-index
    const int jcol = jt * JT + wv * 4 + jj; // global hidden unit
    const int wrow_idx = gown * HID + jcol;

    // B-fragments (gate-interleaved columns) — SHARED by both batch groups
    bf16x8 wfrag[32];
    {
        const unsigned short* wrow = Wc + (size_t)wrow_idx * KTOT;
        #pragma unroll
        for (int kk = 0; kk < 32; ++kk)
            wfrag[kk] = *(const bf16x8*)(wrow + kk * 32 + khi * 8);
    }
    const float biasv = bias[wrow_idx];

    // cell state per group
    float cregA[4], cregB[4];
    #pragma unroll
    for (int R = 0; R < 4; ++R) {
        cregA[R] = c0[(size_t)(btA * BT + khi * 4 + R) * HID + jcol];
        cregB[R] = c0[(size_t)(btB * BT + khi * 4 + R) * HID + jcol];
    }

    const unsigned swz = (unsigned)((ln15 & 7) << 4);
    const int xrow0 = tid >> 7;          // 0..3
    const int xcol4 = tid & 127;

    // poll/pack: quarter q = wv*4+khi (0..31); row = q>>1, half = q&1
    const int q     = wv * 4 + khi;
    const int prow  = q >> 1;
    const int qh    = q & 1;
    const unsigned rsw = (unsigned)((prow & 7) << 4);

    // ---- prologue ----
    #pragma unroll
    for (int i = 0; i < 4; ++i) {
        int row = xrow0 + 4 * i;
        unsigned off = ((unsigned)(xcol4 * 8)) ^ ((unsigned)((row & 7) << 4));
        float4 vA = *(const float4*)(xin + (size_t)(btA * BT + row) * IN + xcol4 * 4);
        *(ushort4*)(smem + (size_t)row * 1024 + off) = pack4(vA);
        float4 vB = *(const float4*)(xin + (size_t)(btB * BT + row) * IN + xcol4 * 4);
        *(ushort4*)(smem + 16384 + (size_t)row * 1024 + off) = pack4(vB);
        float4 hA = *(const float4*)(h0 + (size_t)(btA * BT + row) * HID + xcol4 * 4);
        *(ushort4*)(smem + 32768 + (size_t)row * 1024 + off) = pack4(hA);
        float4 hB = *(const float4*)(h0 + (size_t)(btB * BT + row) * HID + xcol4 * 4);
        *(ushort4*)(smem + 65536 + (size_t)row * 1024 + off) = pack4(hB);
    }
    float4 xrA[4], xrB[4];
    #pragma unroll
    for (int i = 0; i < 4; ++i) {
        xrA[i] = *(const float4*)(xin + (size_t)1 * (BATCH * IN)
                                      + (size_t)(btA * BT + xrow0 + 4 * i) * IN + xcol4 * 4);
        xrB[i] = *(const float4*)(xin + (size_t)1 * (BATCH * IN)
                                      + (size_t)(btB * BT + xrow0 + 4 * i) * IN + xcol4 * 4);
    }
    __syncthreads();

    f32x4 acc_xA0 = {biasv, biasv, biasv, biasv}, acc_xA1 = {0.f, 0.f, 0.f, 0.f};
    f32x4 acc_xB0 = {biasv, biasv, biasv, biasv}, acc_xB1 = {0.f, 0.f, 0.f, 0.f};
    {
        const unsigned char* xa = smem + (size_t)ln15 * 1024;
        const unsigned char* xb = smem + 16384 + (size_t)ln15 * 1024;
        #pragma unroll
        for (int kk = 0; kk < 16; ++kk) {
            unsigned off = ((unsigned)(kk * 64 + khi * 16)) ^ swz;
            bf16x8 afA = *(const bf16x8*)(xa + off);
            bf16x8 afB = *(const bf16x8*)(xb + off);
            if (kk & 1) { acc_xA1 = __builtin_amdgcn_mfma_f32_16x16x32_bf16(afA, wfrag[kk], acc_xA1, 0, 0, 0);
                          acc_xB1 = __builtin_amdgcn_mfma_f32_16x16x32_bf16(afB, wfrag[kk], acc_xB1, 0, 0, 0); }
            else        { acc_xA0 = __builtin_amdgcn_mfma_f32_16x16x32_bf16(afA, wfrag[kk], acc_xA0, 0, 0, 0);
                          acc_xB0 = __builtin_amdgcn_mfma_f32_16x16x32_bf16(afB, wfrag[kk], acc_xB0, 0, 0, 0); }
        }
    }
    __syncthreads();

    #pragma unroll 1
    for (int t = 0; t < T_STEPS; ++t) {
        const unsigned hsA = 32768u + (unsigned)(t & 1) * 16384u;
        const unsigned hsB = 65536u + (unsigned)(t & 1) * 16384u;
        float hRA[4], hRB[4];

        // ======== group A: h-MFMA + act/cell + publish ========
        {
            f32x4 a0 = acc_xA0, a1 = acc_xA1;
            const unsigned char* hp = smem + hsA + (size_t)ln15 * 1024;
            #pragma unroll
            for (int kk = 16; kk < 32; ++kk) {
                unsigned off = ((unsigned)((kk - 16) * 64 + khi * 16)) ^ swz;
                bf16x8 af = *(const bf16x8*)(hp + off);
                if (kk & 1) a1 = __builtin_amdgcn_mfma_f32_16x16x32_bf16(af, wfrag[kk], a1, 0, 0, 0);
                else        a0 = __builtin_amdgcn_mfma_f32_16x16x32_bf16(af, wfrag[kk], a0, 0, 0, 0);
            }
            f32x4 accs = a0 + a1;
            #pragma unroll
            for (int R = 0; R < 4; ++R) {
                float x = accs[R];
                bool isg = (gown == 2);
                float e = __expf(isg ? 2.f * x : -x);
                float r = __builtin_amdgcn_rcpf(1.f + e);
                float a = isg ? 1.f - 2.f * r : r;
                float vi = qbcast<0>(a), vf = qbcast<1>(a), vg = qbcast<2>(a), vo = qbcast<3>(a);
                float c = vf * cregA[R] + vi * vg;
                cregA[R] = c;
                hRA[R] = vo * tanh_fast(c);
            }
            if (t < T_STEPS - 1) {
                #pragma unroll
                for (int R = 0; R < 4; ++R) {
                    if (gown == R) {
                        unsigned w = ((unsigned)(t + 1) << 16) | (unsigned)f2bf(hRA[R]);
                        unsigned* hq = hseq + (size_t)(t & 1) * BH
                                            + (size_t)(btA * BT + khi * 4 + R) * HID + jcol;
                        asm volatile("global_store_dword %0, %1, off sc0 sc1" :: "v"(hq), "v"(w) : "memory");
                    }
                }
            }
            #pragma unroll
            for (int R = 0; R < 4; ++R) {
                if (gown == R)
                    out[(size_t)t * BH + (size_t)(btA * BT + khi * 4 + R) * HID + jcol] = hRA[R];
            }
        }

        // ======== group B: h-MFMA + act/cell + publish ========
        {
            f32x4 a0 = acc_xB0, a1 = acc_xB1;
            const unsigned char* hp = smem + hsB + (size_t)ln15 * 1024;
            #pragma unroll
            for (int kk = 16; kk < 32; ++kk) {
                unsigned off = ((unsigned)((kk - 16) * 64 + khi * 16)) ^ swz;
                bf16x8 af = *(const bf16x8*)(hp + off);
                if (kk & 1) a1 = __builtin_amdgcn_mfma_f32_16x16x32_bf16(af, wfrag[kk], a1, 0, 0, 0);
                else        a0 = __builtin_amdgcn_mfma_f32_16x16x32_bf16(af, wfrag[kk], a0, 0, 0, 0);
            }
            f32x4 accs = a0 + a1;
            #pragma unroll
            for (int R = 0; R < 4; ++R) {
                float x = accs[R];
                bool isg = (gown == 2);
                float e = __expf(isg ? 2.f * x : -x);
                float r = __builtin_amdgcn_rcpf(1.f + e);
                float a = isg ? 1.f - 2.f * r : r;
                float vi = qbcast<0>(a), vf = qbcast<1>(a), vg = qbcast<2>(a), vo = qbcast<3>(a);
                float c = vf * cregB[R] + vi * vg;
                cregB[R] = c;
                hRB[R] = vo * tanh_fast(c);
            }
            if (t < T_STEPS - 1) {
                #pragma unroll
                for (int R = 0; R < 4; ++R) {
                    if (gown == R) {
                        unsigned w = ((unsigned)(t + 1) << 16) | (unsigned)f2bf(hRB[R]);
                        unsigned* hq = hseq + (size_t)(t & 1) * BH
                                            + (size_t)(btB * BT + khi * 4 + R) * HID + jcol;
                        asm volatile("global_store_dword %0, %1, off sc0 sc1" :: "v"(hq), "v"(w) : "memory");
                    }
                }
            }
            #pragma unroll
            for (int R = 0; R < 4; ++R) {
                if (gown == R)
                    out[(size_t)t * BH + (size_t)(btB * BT + khi * 4 + R) * HID + jcol] = hRB[R];
            }
        }

        if (t == T_STEPS - 1) {
            size_t base = (size_t)T_STEPS * BH;
            #pragma unroll
            for (int R = 0; R < 4; ++R) {
                if (gown == R) {
                    size_t oA = (size_t)(btA * BT + khi * 4 + R) * HID + jcol;
                    out[base + oA] = hRA[R];
                    out[base + BH + oA] = cregA[R];
                    size_t oB = (size_t)(btB * BT + khi * 4 + R) * HID + jcol;
                    out[base + oB] = hRB[R];
                    out[base + BH + oB] = cregB[R];
                }
            }
        } else {
            // ---- stage x_{t+1} for A,B ----
            #pragma unroll
            for (int i = 0; i < 4; ++i) {
                int row = xrow0 + 4 * i;
                unsigned off = ((unsigned)(xcol4 * 8)) ^ ((unsigned)((row & 7) << 4));
                *(ushort4*)(smem + (size_t)row * 1024 + off) = pack4(xrA[i]);
                *(ushort4*)(smem + 16384 + (size_t)row * 1024 + off) = pack4(xrB[i]);
            }
            asm volatile("s_waitcnt lgkmcnt(0)" ::: "memory");
            __builtin_amdgcn_s_barrier();

            // ---- issue sweeps for A and B (8 loads, oldest in queue) ----
            const unsigned* ppA = hseq + (size_t)(t & 1) * BH
                                       + (size_t)(btA * BT + prow) * HID + qh * 256 + ln15 * 4;
            const unsigned* ppB = hseq + (size_t)(t & 1) * BH
                                       + (size_t)(btB * BT + prow) * HID + qh * 256 + ln15 * 4;
            const unsigned tgtw = (unsigned)(t + 1) << 16;
            u32x4 hA0, hA1, hA2, hA3, hB0, hB1, hB2, hB3;
            asm volatile(
                "global_load_dwordx4 %0, %8, off offset:0 sc0 sc1\n\t"
                "global_load_dwordx4 %1, %8, off offset:256 sc0 sc1\n\t"
                "global_load_dwordx4 %2, %8, off offset:512 sc0 sc1\n\t"
                "global_load_dwordx4 %3, %8, off offset:768 sc0 sc1\n\t"
                "global_load_dwordx4 %4, %9, off offset:0 sc0 sc1\n\t"
                "global_load_dwordx4 %5, %9, off offset:256 sc0 sc1\n\t"
                "global_load_dwordx4 %6, %9, off offset:512 sc0 sc1\n\t"
                "global_load_dwordx4 %7, %9, off offset:768 sc0 sc1"
                : "=&v"(hA0), "=&v"(hA1), "=&v"(hA2), "=&v"(hA3),
                  "=&v"(hB0), "=&v"(hB1), "=&v"(hB2), "=&v"(hB3)
                : "v"(ppA), "v"(ppB) : "memory");

            // ---- prefetch x_{t+2} (8 loads, stay in flight past vmcnt(8)) ----
            {
                int tn = (t + 2) & (T_STEPS - 1);
                #pragma unroll
                for (int i = 0; i < 4; ++i) {
                    xrA[i] = *(const float4*)(xin + (size_t)tn * (BATCH * IN)
                                                  + (size_t)(btA * BT + xrow0 + 4 * i) * IN + xcol4 * 4);
                    xrB[i] = *(const float4*)(xin + (size_t)tn * (BATCH * IN)
                                                  + (size_t)(btB * BT + xrow0 + 4 * i) * IN + xcol4 * 4);
                }
            }

            // ---- x-MFMA for t+1, both groups (sweep flight hides under this) ----
            acc_xA0 = f32x4{biasv, biasv, biasv, biasv}; acc_xA1 = f32x4{0.f, 0.f, 0.f, 0.f};
            acc_xB0 = f32x4{biasv, biasv, biasv, biasv}; acc_xB1 = f32x4{0.f, 0.f, 0.f, 0.f};
            {
                const unsigned char* xa = smem + (size_t)ln15 * 1024;
                const unsigned char* xb = smem + 16384 + (size_t)ln15 * 1024;
                #pragma unroll
                for (int kk = 0; kk < 16; ++kk) {
                    unsigned off = ((unsigned)(kk * 64 + khi * 16)) ^ swz;
                    bf16x8 afA = *(const bf16x8*)(xa + off);
                    bf16x8 afB = *(const bf16x8*)(xb + off);
                    if (kk & 1) { acc_xA1 = __builtin_amdgcn_mfma_f32_16x16x32_bf16(afA, wfrag[kk], acc_xA1, 0, 0, 0);
                                  acc_xB1 = __builtin_amdgcn_mfma_f32_16x16x32_bf16(afB, wfrag[kk], acc_xB1, 0, 0, 0); }
                    else        { acc_xA0 = __builtin_amdgcn_mfma_f32_16x16x32_bf16(afA, wfrag[kk], acc_xA0, 0, 0, 0);
                                  acc_xB0 = __builtin_amdgcn_mfma_f32_16x16x32_bf16(afB, wfrag[kk], acc_xB0, 0, 0, 0); }
                }
            }

            // ---- wait sweeps only (8 x loads keep flying), validate, resweep ----
            asm volatile("s_waitcnt vmcnt(8)" ::: "memory");
            __builtin_amdgcn_sched_barrier(0);
            for (;;) {
                bool ok = vld4(hA0, tgtw) & vld4(hA1, tgtw) & vld4(hA2, tgtw) & vld4(hA3, tgtw)
                        & vld4(hB0, tgtw) & vld4(hB1, tgtw) & vld4(hB2, tgtw) & vld4(hB3, tgtw);
                if (__ballot(ok) == ~0ull) break;
                asm volatile(
                    "global_load_dwordx4 %0, %8, off offset:0 sc0 sc1\n\t"
                    "global_load_dwordx4 %1, %8, off offset:256 sc0 sc1\n\t"
                    "global_load_dwordx4 %2, %8, off offset:512 sc0 sc1\n\t"
                    "global_load_dwordx4 %3, %8, off offset:768 sc0 sc1\n\t"
                    "global_load_dwordx4 %4, %9, off offset:0 sc0 sc1\n\t"
                    "global_load_dwordx4 %5, %9, off offset:256 sc0 sc1\n\t"
                    "global_load_dwordx4 %6, %9, off offset:512 sc0 sc1\n\t"
                    "global_load_dwordx4 %7, %9, off offset:768 sc0 sc1\n\t"
                    "s_waitcnt vmcnt(0)"
                    : "=&v"(hA0), "=&v"(hA1), "=&v"(hA2), "=&v"(hA3),
                      "=&v"(hB0), "=&v"(hB1), "=&v"(hB2), "=&v"(hB3)
                    : "v"(ppA), "v"(ppB) : "memory");
                __builtin_amdgcn_sched_barrier(0);
            }

            // ---- pack polled h_t -> h slots [(t+1)&1] for A,B ----
            {
                unsigned wbA = 32768u + (unsigned)((t + 1) & 1) * 16384u + (unsigned)prow * 1024u;
                unsigned wbB = 65536u + (unsigned)((t + 1) & 1) * 16384u + (unsigned)prow * 1024u;
                const u32x4 hvA[4] = {hA0, hA1, hA2, hA3};
                const u32x4 hvB[4] = {hB0, hB1, hB2, hB3};
                #pragma unroll
                for (int sq = 0; sq < 4; ++sq) {
                    unsigned off = ((unsigned)(qh * 512 + sq * 128 + ln15 * 8)) ^ rsw;
                    uint2 pkA, pkB;
                    pkA.x = (hvA[sq][0] & 0xFFFFu) | (hvA[sq][1] << 16);
                    pkA.y = (hvA[sq][2] & 0xFFFFu) | (hvA[sq][3] << 16);
                    pkB.x = (hvB[sq][0] & 0xFFFFu) | (hvB[sq][1] << 16);
                    pkB.y = (hvB[sq][2] & 0xFFFFu) | (hvB[sq][3] << 16);
                    *(uint2*)(smem + wbA + off) = pkA;
                    *(uint2*)(smem + wbB + off) = pkB;
                }
            }

            asm volatile("s_waitcnt lgkmcnt(0)" ::: "memory");
            __builtin_amdgcn_s_barrier();
        }
    }
}

extern "C" void kernel_launch(void* const* d_in, const int* in_sizes, int n_in,
                              void* d_out, int out_size, void* d_ws, size_t ws_size,
                              hipStream_t stream) {
    const float* input = (const float*)d_in[0];
    const float* h0    = (const float*)d_in[1];
    const float* c0    = (const float*)d_in[2];
    const float* W_ih  = (const float*)d_in[3];
    const float* W_hh  = (const float*)d_in[4];
    const float* b_ih  = (const float*)d_in[5];
    const float* b_hh  = (const float*)d_in[6];
    float* out = (float*)d_out;

    char* ws = (char*)d_ws;
    unsigned* hseq = (unsigned*)ws;                            // 2*128*512*4 = 512 KB
    float*    bias = (float*)(ws + 512 * 1024);                // 8 KB
    unsigned short* Wc = (unsigned short*)(ws + 512 * 1024 + 16 * 1024);  // 4 MB

    hipMemsetAsync(hseq, 0, 2 * BH * sizeof(unsigned), stream);
    prep_kernel<<<2048, 256, 0, stream>>>(W_ih, W_hh, b_ih, b_hh, Wc, bias);
    lstm_kernel<<<NJT * 4, 512, 0, stream>>>(input, h0, c0, Wc, bias, out, hseq);
}

// Round 14
// 1867.278 us; speedup vs baseline: 3.6580x; 3.6580x over previous
//
#include <hip/hip_runtime.h>
#include <hip/hip_bf16.h>

#define T_STEPS 512
#define BATCH   128
#define IN      512
#define HID     512
#define KTOT    1024   // IN + HID fused
#define BT      16     // batch rows per block
#define JT      32     // hidden cols per block
#define NBT     8      // batch groups
#define NJT     16     // blocks per group
#define BH      (BATCH * HID)

typedef __attribute__((ext_vector_type(8))) short bf16x8;
typedef __attribute__((ext_vector_type(4))) float f32x4;
typedef __attribute__((ext_vector_type(4))) unsigned int u32x4;

static __device__ __forceinline__ unsigned short f2bf(float f) {
    unsigned u = __float_as_uint(f);
    unsigned r = (u + 0x7FFFu + ((u >> 16) & 1u)) >> 16;   // RNE, finite inputs only
    return (unsigned short)r;
}
static __device__ __forceinline__ ushort4 pack4(float4 v) {
    ushort4 b4;
    b4.x = f2bf(v.x); b4.y = f2bf(v.y); b4.z = f2bf(v.z); b4.w = f2bf(v.w);
    return b4;
}
static __device__ __forceinline__ float tanh_fast(float x) {
    return 1.f - 2.f * __builtin_amdgcn_rcpf(1.f + __expf(2.f * x));
}
static __device__ __forceinline__ bool vld4(u32x4 v, unsigned tgtw) {
    return ((v[0] & 0xFFFF0000u) == tgtw) & ((v[1] & 0xFFFF0000u) == tgtw) &
           ((v[2] & 0xFFFF0000u) == tgtw) & ((v[3] & 0xFFFF0000u) == tgtw);
}
template<int I>
static __device__ __forceinline__ float qbcast(float x) {   // broadcast quad-lane I within each quad (DPP)
    return __uint_as_float((unsigned)__builtin_amdgcn_update_dpp(
        (int)__float_as_uint(x), (int)__float_as_uint(x), I * 0x55, 0xF, 0xF, false));
}

// ---- prep: fuse W_ih|W_hh into bf16 [2048][1024], bias = b_ih + b_hh ----
__global__ void prep_kernel(const float* __restrict__ W_ih, const float* __restrict__ W_hh,
                            const float* __restrict__ b_ih, const float* __restrict__ b_hh,
                            unsigned short* __restrict__ Wc, float* __restrict__ bias) {
    int idx = blockIdx.x * blockDim.x + threadIdx.x;   // 0 .. 2048*256-1 float4 granules
    int row = idx >> 8;
    int kq  = idx & 255;
    const float* src = (kq < 128) ? (W_ih + (size_t)row * IN + kq * 4)
                                  : (W_hh + (size_t)row * HID + (kq - 128) * 4);
    float4 v = *(const float4*)src;
    *(ushort4*)(Wc + (size_t)row * KTOT + kq * 4) = pack4(v);
    if (idx < 4 * HID) bias[idx] = b_ih[idx] + b_hh[idx];
}

// ---- persistent LSTM kernel: 512 threads, 8 waves, 16 batch x 32 hidden per block ----
__global__ __launch_bounds__(512, 2) void lstm_kernel(
    const float* __restrict__ xin, const float* __restrict__ h0,
    const float* __restrict__ c0, const unsigned short* __restrict__ Wc,
    const float* __restrict__ bias, float* __restrict__ out,
    unsigned* __restrict__ hseq)   // [2][BATCH][HID] u32: (seq<<16)|bf16(h)
{
    const int tid  = threadIdx.x;
    const int bid  = blockIdx.x;
    const int bt   = bid & 7;        // batch group
    const int jt   = bid >> 3;       // j tile 0..15 (32 cols each)
    const int wv   = tid >> 6;       // wave id 0..7
    const int lane = tid & 63;
    const int ln15 = lane & 15;
    const int khi  = lane >> 4;

    // x slot [0,16K); h slots [16K,32K),[32K,48K)
    __shared__ __align__(16) unsigned char smem[49152];

    const int gown = ln15 & 3;              // lane's gate (0=i,1=f,2=g,3=o)
    const int jj   = ln15 >> 2;             // j sub-index
    const int jcol = jt * JT + wv * 4 + jj; // global hidden unit
    const int wrow_idx = gown * HID + jcol;

    // B-fragments (gate-interleaved columns) in VGPRs
    bf16x8 wfrag[32];
    {
        const unsigned short* wrow = Wc + (size_t)wrow_idx * KTOT;
        #pragma unroll
        for (int kk = 0; kk < 32; ++kk)
            wfrag[kk] = *(const bf16x8*)(wrow + kk * 32 + khi * 8);
    }
    const float biasv = bias[wrow_idx];

    // cell state: creg[R] = c(b = khi*4+R, jcol), 4x redundant across gate lanes
    float creg[4];
    #pragma unroll
    for (int R = 0; R < 4; ++R)
        creg[R] = c0[(size_t)(bt * BT + khi * 4 + R) * HID + jcol];

    const unsigned swz = (unsigned)((ln15 & 7) << 4);
    const int xrow0 = tid >> 7;          // 0..3
    const int xcol4 = tid & 127;         // float4 granule within 512-wide fp32 row

    // poll/pack mapping: quarter q = wv*4+khi (0..31); row = q>>1, half = q&1 (256 cols)
    const int q     = wv * 4 + khi;
    const int prow  = q >> 1;
    const int qh    = q & 1;
    const unsigned rsw = (unsigned)((prow & 7) << 4);

    // ---- prologue: stage x0 -> xslot, h0 -> hslot0; prefetch x1; x-MFMA(step0) ----
    #pragma unroll
    for (int i = 0; i < 4; ++i) {
        int row = xrow0 + 4 * i;
        unsigned off = ((unsigned)(xcol4 * 8)) ^ ((unsigned)((row & 7) << 4));
        float4 vx = *(const float4*)(xin + (size_t)(bt * BT + row) * IN + xcol4 * 4);
        *(ushort4*)(smem + (size_t)row * 1024 + off) = pack4(vx);
        float4 vh = *(const float4*)(h0 + (size_t)(bt * BT + row) * HID + xcol4 * 4);
        *(ushort4*)(smem + 16384 + (size_t)row * 1024 + off) = pack4(vh);
    }
    float4 xr[4];
    #pragma unroll
    for (int i = 0; i < 4; ++i)
        xr[i] = *(const float4*)(xin + (size_t)1 * (BATCH * IN)
                                     + (size_t)(bt * BT + xrow0 + 4 * i) * IN + xcol4 * 4);
    __syncthreads();

    f32x4 acc_x0 = {biasv, biasv, biasv, biasv};
    f32x4 acc_x1 = {0.f, 0.f, 0.f, 0.f};
    {
        const unsigned char* xrow_p = smem + (size_t)ln15 * 1024;
        #pragma unroll
        for (int kk = 0; kk < 16; ++kk) {
            unsigned off = ((unsigned)(kk * 64 + khi * 16)) ^ swz;
            bf16x8 af = *(const bf16x8*)(xrow_p + off);
            if (kk & 1) acc_x1 = __builtin_amdgcn_mfma_f32_16x16x32_bf16(af, wfrag[kk], acc_x1, 0, 0, 0);
            else        acc_x0 = __builtin_amdgcn_mfma_f32_16x16x32_bf16(af, wfrag[kk], acc_x0, 0, 0, 0);
        }
    }
    __syncthreads();

    #pragma unroll 1
    for (int t = 0; t < T_STEPS; ++t) {
        // ---- P1: h-MFMA (h_{t-1} in hslot[t&1]); acc seeded with x-part(t) ----
        const unsigned hbase = 16384u + (unsigned)(t & 1) * 16384u;
        f32x4 acc0 = acc_x0;
        f32x4 acc1 = acc_x1;
        const unsigned char* hrow_p = smem + hbase + (size_t)ln15 * 1024;
        #pragma unroll
        for (int kk = 16; kk < 32; ++kk) {
            unsigned off = ((unsigned)((kk - 16) * 64 + khi * 16)) ^ swz;
            bf16x8 af = *(const bf16x8*)(hrow_p + off);
            if (kk & 1) acc1 = __builtin_amdgcn_mfma_f32_16x16x32_bf16(af, wfrag[kk], acc1, 0, 0, 0);
            else        acc0 = __builtin_amdgcn_mfma_f32_16x16x32_bf16(af, wfrag[kk], acc0, 0, 0, 0);
        }
        f32x4 accs = acc0 + acc1;

        // ---- P2: act + DPP gate exchange + cell update + IMMEDIATE publish ----
        float hR[4];
        #pragma unroll
        for (int R = 0; R < 4; ++R) {
            float x = accs[R];
            bool isg = (gown == 2);
            float e = __expf(isg ? 2.f * x : -x);
            float r = __builtin_amdgcn_rcpf(1.f + e);
            float a = isg ? 1.f - 2.f * r : r;
            float vi = qbcast<0>(a), vf = qbcast<1>(a), vg = qbcast<2>(a), vo = qbcast<3>(a);
            float c = vf * creg[R] + vi * vg;
            creg[R] = c;
            float h = vo * tanh_fast(c);
            hR[R] = h;
            if (t < T_STEPS - 1 && gown == R) {
                unsigned w = ((unsigned)(t + 1) << 16) | (unsigned)f2bf(h);
                unsigned* hp = hseq + (size_t)(t & 1) * BH
                                    + (size_t)(bt * BT + khi * 4 + R) * HID + jcol;
                asm volatile("global_store_dword %0, %1, off sc0 sc1"
                             :: "v"(hp), "v"(w) : "memory");
            }
            if (gown == R)
                out[(size_t)t * BH + (size_t)(bt * BT + khi * 4 + R) * HID + jcol] = h;
        }

        if (t == T_STEPS - 1) {
            // ---- epilogue: hT, cT ----
            size_t base = (size_t)T_STEPS * BH;
            #pragma unroll
            for (int R = 0; R < 4; ++R) {
                if (gown == R) {
                    size_t o2 = (size_t)(bt * BT + khi * 4 + R) * HID + jcol;
                    out[base + o2] = hR[R];
                    out[base + BH + o2] = creg[R];
                }
            }
        } else {
            // ---- P3: stage x_{t+1} (xr) -> xslot ----
            #pragma unroll
            for (int i = 0; i < 4; ++i) {
                int row = xrow0 + 4 * i;
                unsigned off = ((unsigned)(xcol4 * 8)) ^ ((unsigned)((row & 7) << 4));
                *(ushort4*)(smem + (size_t)row * 1024 + off) = pack4(xr[i]);
            }

            // ---- B1: make xslot visible across waves ----
            asm volatile("s_waitcnt lgkmcnt(0)" ::: "memory");
            __builtin_amdgcn_s_barrier();

            // ---- P4: sweep S0 issued now (flies under x-MFMA) ----
            const unsigned* pp = hseq + (size_t)(t & 1) * BH
                                      + (size_t)(bt * BT + prow) * HID + qh * 256 + ln15 * 4;
            const unsigned tgtw = (unsigned)(t + 1) << 16;
            u32x4 hv0, hv1, hv2, hv3;
            asm volatile(
                "global_load_dwordx4 %0, %4, off offset:0 sc0 sc1\n\t"
                "global_load_dwordx4 %1, %4, off offset:256 sc0 sc1\n\t"
                "global_load_dwordx4 %2, %4, off offset:512 sc0 sc1\n\t"
                "global_load_dwordx4 %3, %4, off offset:768 sc0 sc1"
                : "=&v"(hv0), "=&v"(hv1), "=&v"(hv2), "=&v"(hv3)
                : "v"(pp) : "memory");

            // ---- P5: x-MFMA first half ----
            acc_x0 = f32x4{biasv, biasv, biasv, biasv};
            acc_x1 = f32x4{0.f, 0.f, 0.f, 0.f};
            const unsigned char* xrow_p = smem + (size_t)ln15 * 1024;
            #pragma unroll
            for (int kk = 0; kk < 8; ++kk) {
                unsigned off = ((unsigned)(kk * 64 + khi * 16)) ^ swz;
                bf16x8 af = *(const bf16x8*)(xrow_p + off);
                if (kk & 1) acc_x1 = __builtin_amdgcn_mfma_f32_16x16x32_bf16(af, wfrag[kk], acc_x1, 0, 0, 0);
                else        acc_x0 = __builtin_amdgcn_mfma_f32_16x16x32_bf16(af, wfrag[kk], acc_x0, 0, 0, 0);
            }

            // ---- P6: sweep S1 (staggered ~300cy after S0) ----
            u32x4 hw0, hw1, hw2, hw3;
            asm volatile(
                "global_load_dwordx4 %0, %4, off offset:0 sc0 sc1\n\t"
                "global_load_dwordx4 %1, %4, off offset:256 sc0 sc1\n\t"
                "global_load_dwordx4 %2, %4, off offset:512 sc0 sc1\n\t"
                "global_load_dwordx4 %3, %4, off offset:768 sc0 sc1"
                : "=&v"(hw0), "=&v"(hw1), "=&v"(hw2), "=&v"(hw3)
                : "v"(pp) : "memory");

            // ---- P7: x-MFMA second half ----
            #pragma unroll
            for (int kk = 8; kk < 16; ++kk) {
                unsigned off = ((unsigned)(kk * 64 + khi * 16)) ^ swz;
                bf16x8 af = *(const bf16x8*)(xrow_p + off);
                if (kk & 1) acc_x1 = __builtin_amdgcn_mfma_f32_16x16x32_bf16(af, wfrag[kk], acc_x1, 0, 0, 0);
                else        acc_x0 = __builtin_amdgcn_mfma_f32_16x16x32_bf16(af, wfrag[kk], acc_x0, 0, 0, 0);
            }

            // ---- P8: prefetch x_{t+2} LAST (youngest in vm queue, stays in flight) ----
            {
                int tn = (t + 2) & (T_STEPS - 1);
                #pragma unroll
                for (int i = 0; i < 4; ++i)
                    xr[i] = *(const float4*)(xin + (size_t)tn * (BATCH * IN)
                                                 + (size_t)(bt * BT + xrow0 + 4 * i) * IN + xcol4 * 4);
            }

            // ---- P9: retire S0 (S1 + prefetch outstanding = 8), detect, fall back ----
            asm volatile("s_waitcnt vmcnt(8)" ::: "memory");
            __builtin_amdgcn_sched_barrier(0);
            bool ok0 = vld4(hv0, tgtw) & vld4(hv1, tgtw) & vld4(hv2, tgtw) & vld4(hv3, tgtw);
            if (__ballot(ok0) == ~0ull) {
                asm volatile("s_waitcnt vmcnt(4)" ::: "memory");   // retire S1; prefetch keeps flying
            } else {
                asm volatile("s_waitcnt vmcnt(4)" ::: "memory");   // S1 done
                __builtin_amdgcn_sched_barrier(0);
                bool ok1 = vld4(hw0, tgtw) & vld4(hw1, tgtw) & vld4(hw2, tgtw) & vld4(hw3, tgtw);
                if (__ballot(ok1) == ~0ull) {
                    hv0 = hw0; hv1 = hw1; hv2 = hw2; hv3 = hw3;
                } else {
                    for (;;) {
                        asm volatile(
                            "global_load_dwordx4 %0, %4, off offset:0 sc0 sc1\n\t"
                            "global_load_dwordx4 %1, %4, off offset:256 sc0 sc1\n\t"
                            "global_load_dwordx4 %2, %4, off offset:512 sc0 sc1\n\t"
                            "global_load_dwordx4 %3, %4, off offset:768 sc0 sc1\n\t"
                            "s_waitcnt vmcnt(0)"
                            : "=&v"(hv0), "=&v"(hv1), "=&v"(hv2), "=&v"(hv3)
                            : "v"(pp) : "memory");
                        __builtin_amdgcn_sched_barrier(0);
                        bool ok = vld4(hv0, tgtw) & vld4(hv1, tgtw) & vld4(hv2, tgtw) & vld4(hv3, tgtw);
                        if (__ballot(ok) == ~0ull) break;
                    }
                }
            }

            // ---- P10: pack polled half-row -> hslot[(t+1)&1] ----
            {
                unsigned hnb = 16384u + (unsigned)((t + 1) & 1) * 16384u;
                unsigned wbase = hnb + (unsigned)prow * 1024u;
                const u32x4 hv[4] = {hv0, hv1, hv2, hv3};
                #pragma unroll
                for (int sq = 0; sq < 4; ++sq) {
                    uint2 pk;
                    pk.x = (hv[sq][0] & 0xFFFFu) | (hv[sq][1] << 16);
                    pk.y = (hv[sq][2] & 0xFFFFu) | (hv[sq][3] << 16);
                    unsigned off = ((unsigned)(qh * 512 + sq * 128 + ln15 * 8)) ^ rsw;
                    *(uint2*)(smem + wbase + off) = pk;
                }
            }

            // ---- B2: h slot visible ----
            asm volatile("s_waitcnt lgkmcnt(0)" ::: "memory");
            __builtin_amdgcn_s_barrier();
        }
    }
}

extern "C" void kernel_launch(void* const* d_in, const int* in_sizes, int n_in,
                              void* d_out, int out_size, void* d_ws, size_t ws_size,
                              hipStream_t stream) {
    const float* input = (const float*)d_in[0];
    const float* h0    = (const float*)d_in[1];
    const float* c0    = (const float*)d_in[2];
    const float* W_ih  = (const float*)d_in[3];
    const float* W_hh  = (const float*)d_in[4];
    const float* b_ih  = (const float*)d_in[5];
    const float* b_hh  = (const float*)d_in[6];
    float* out = (float*)d_out;

    char* ws = (char*)d_ws;
    unsigned* hseq = (unsigned*)ws;                            // 2*128*512*4 = 512 KB
    float*    bias = (float*)(ws + 512 * 1024);                // 8 KB
    unsigned short* Wc = (unsigned short*)(ws + 512 * 1024 + 16 * 1024);  // 4 MB

    hipMemsetAsync(hseq, 0, 2 * BH * sizeof(unsigned), stream);
    prep_kernel<<<2048, 256, 0, stream>>>(W_ih, W_hh, b_ih, b_hh, Wc, bias);
    lstm_kernel<<<NBT * NJT, 512, 0, stream>>>(input, h0, c0, Wc, bias, out, hseq);
}